// Round 5
// baseline (140.418 us; speedup 1.0000x reference)
//
#include <hip/hip_runtime.h>
#include <hip/hip_bf16.h>

#define B_ 32
#define T_ 4096
#define H_ 512
#define TILE_T 4
#define M_TILE 128   // TILE_T * B_
#define BK 64
#define KSTEPS 8     // H_ / BK
#define NTHREADS 256 // 4 waves; 2 blocks co-resident per CU

typedef __attribute__((ext_vector_type(8))) short short8;
typedef __attribute__((ext_vector_type(8))) __bf16 bf16x8;
typedef __attribute__((ext_vector_type(4))) float f32x4;

__device__ __forceinline__ short f2bf(float f) {
    unsigned u = __builtin_bit_cast(unsigned, f);
    u = (u + 0x7fffu + ((u >> 16) & 1u)) >> 16;
    return (short)u;
}

// ---- prep: W2 -> bf16 fragment-packed for direct global->reg B-frag loads ----
// w2f[c][kk][ks][ni][lane][j]  (c=col block 0..7, kk=kstep 0..7, ks=0..1, ni=0..3)
// lane's frag element j maps to h = c*64+ni*16+(lane&15), k = kk*64+ks*32+(lane>>4)*8+j
__global__ void prep_w2f(const float* __restrict__ W, short* __restrict__ w2f) {
    int idx = blockIdx.x * 256 + threadIdx.x;   // 0 .. 262143
    int j    = idx & 7;
    int lane = (idx >> 3) & 63;
    int ni   = (idx >> 9) & 3;
    int ks   = (idx >> 11) & 1;
    int kk   = (idx >> 12) & 7;
    int c    = (idx >> 15) & 7;
    int h = c * 64 + ni * 16 + (lane & 15);
    int k = kk * 64 + ks * 32 + (lane >> 4) * 8 + j;
    w2f[idx] = f2bf(W[h * (2 * H_) + H_ + k]);
}

// ---- prep: hid_proj[b][h] = hidden[b,:]*W1[h,:] + bias[h] (f32 exact) ----
__global__ void prep_hid(const float* __restrict__ hidden,
                         const float* __restrict__ W,
                         const float* __restrict__ bias,
                         float* __restrict__ hidproj) {
    __shared__ float hrow[H_];
    int b = blockIdx.y;
    int h = blockIdx.x * 128 + threadIdx.x;
    for (int i = threadIdx.x; i < H_; i += 128) hrow[i] = hidden[b * H_ + i];
    __syncthreads();
    const float* wr = W + (size_t)h * (2 * H_);
    float acc = bias[h];
#pragma unroll 4
    for (int k = 0; k < H_; k += 4) {
        acc += hrow[k]     * wr[k];
        acc += hrow[k + 1] * wr[k + 1];
        acc += hrow[k + 2] * wr[k + 2];
        acc += hrow[k + 3] * wr[k + 3];
    }
    hidproj[b * H_ + h] = acc;
}

// ---- finisher: out[b,t] = relu(sp0 + sp1) ----
__global__ void finish(const float* __restrict__ sp, float* __restrict__ out) {
    int i = blockIdx.x * 256 + threadIdx.x;   // 0 .. 131071
    out[i] = fmaxf(sp[i] + sp[131072 + i], 0.f);
}

// ---- main: 256-thr blocks (4 waves), N-split halves, A-only LDS dbuf ----
__global__ __launch_bounds__(NTHREADS, 2)
void attn_main(const float* __restrict__ enc,      // [T][B][H] f32
               const float* __restrict__ hidproj,  // [B][H] f32
               const short* __restrict__ w2f,      // frag-packed bf16 W2
               const float* __restrict__ vvec,     // [H]
               float* __restrict__ spart)          // [2][B*T] partial scores
{
    __shared__ __align__(16) short lds_a[2][M_TILE * BK];  // 2 x 16 KB

    const int tid  = threadIdx.x;
    const int lane = tid & 63;
    const int wid  = tid >> 6;          // 0..3
    const int bid  = blockIdx.x;
    // pair (eta=0,1) of same tau -> same XCD, adjacent dispatch (bids differ by 8)
    const int tau  = ((bid >> 4) << 3) | (bid & 7);   // 0..1023
    const int eta  = (bid >> 3) & 1;                  // 0..1
    const int t0   = tau * TILE_T;
    const int lo   = lane & 15;
    const int hi4  = lane >> 4;
    const int cblk = eta * 4 + wid;     // col block 0..7 (64 h each)

    f32x4 acc[8][4];
#pragma unroll
    for (int i = 0; i < 8; ++i)
#pragma unroll
        for (int j = 0; j < 4; ++j) acc[i][j] = f32x4{0.f, 0.f, 0.f, 0.f};

    const short* wbase = w2f + (size_t)cblk * 32768 + lane * 8;

    // A staging map: thread -> row (0..127) via tid>>1, half-row ah = tid&1 (32 f32)
    const int arow = tid >> 1;
    const int ah   = tid & 1;
    const float* abase = enc + (size_t)(t0 * B_ + arow) * H_ + ah * 32;
    // 4 swizzled short8 slots (chunks 4ah..4ah+3, XOR row&7)
    const int aw0 = arow * BK + (((4 * ah + 0) ^ (arow & 7)) << 3);
    const int aw1 = arow * BK + (((4 * ah + 1) ^ (arow & 7)) << 3);
    const int aw2 = arow * BK + (((4 * ah + 2) ^ (arow & 7)) << 3);
    const int aw3 = arow * BK + (((4 * ah + 3) ^ (arow & 7)) << 3);

#define CVT2(P, XA, XB)                                                         \
    P[0]=f2bf(XA[0]); P[1]=f2bf(XA[1]); P[2]=f2bf(XA[2]); P[3]=f2bf(XA[3]);     \
    P[4]=f2bf(XB[0]); P[5]=f2bf(XB[1]); P[6]=f2bf(XB[2]); P[7]=f2bf(XB[3]);

    // ---- prologue: stage A(0) into lds_a[0] ----
    {
        f32x4 x0 = *(const f32x4*)(abase);
        f32x4 x1 = *(const f32x4*)(abase + 4);
        f32x4 x2 = *(const f32x4*)(abase + 8);
        f32x4 x3 = *(const f32x4*)(abase + 12);
        f32x4 x4 = *(const f32x4*)(abase + 16);
        f32x4 x5 = *(const f32x4*)(abase + 20);
        f32x4 x6 = *(const f32x4*)(abase + 24);
        f32x4 x7 = *(const f32x4*)(abase + 28);
        short8 p0, p1, p2, p3;
        CVT2(p0, x0, x1) CVT2(p1, x2, x3) CVT2(p2, x4, x5) CVT2(p3, x6, x7)
        *(short8*)&lds_a[0][aw0] = p0;
        *(short8*)&lds_a[0][aw1] = p1;
        *(short8*)&lds_a[0][aw2] = p2;
        *(short8*)&lds_a[0][aw3] = p3;
        asm volatile("s_waitcnt lgkmcnt(0)" ::: "memory");
        __builtin_amdgcn_s_barrier();
    }

    for (int kk = 0; kk < KSTEPS; ++kk) {
        const int cur = kk & 1;
        const bool pf = (kk + 1) < KSTEPS;
        const short* __restrict__ ab = &lds_a[cur][0];
        short* __restrict__ adst = &lds_a[cur ^ 1][0];

        // ---- B-frag loads for this kstep (L2-resident, coalesced 16B/lane) ----
        bf16x8 b0[4], b1[4];
#pragma unroll
        for (int ni = 0; ni < 4; ++ni)
            b0[ni] = *(const bf16x8*)(wbase + ((kk * 2 + 0) * 4 + ni) * 512);
#pragma unroll
        for (int ni = 0; ni < 4; ++ni)
            b1[ni] = *(const bf16x8*)(wbase + ((kk * 2 + 1) * 4 + ni) * 512);

        // ---- A global loads for kstep kk+1 (HBM; hidden under MFMA region) ----
        f32x4 x0, x1, x2, x3, x4, x5, x6, x7;
        if (pf) {
            const float* asrc = abase + (size_t)(kk + 1) * BK;
            x0 = *(const f32x4*)(asrc);      x1 = *(const f32x4*)(asrc + 4);
            x2 = *(const f32x4*)(asrc + 8);  x3 = *(const f32x4*)(asrc + 12);
            x4 = *(const f32x4*)(asrc + 16); x5 = *(const f32x4*)(asrc + 20);
            x6 = *(const f32x4*)(asrc + 24); x7 = *(const f32x4*)(asrc + 28);
        }

        // ---- ks = 0 ----
        {
            bf16x8 af[4];
#pragma unroll
            for (int mi = 0; mi < 4; ++mi) {
                int r = mi * 16 + lo;
                af[mi] = *(const bf16x8*)&ab[r * BK + ((hi4 ^ (r & 7)) << 3)];
            }
            __builtin_amdgcn_s_setprio(1);
#pragma unroll
            for (int mi = 0; mi < 4; ++mi)
#pragma unroll
                for (int ni = 0; ni < 4; ++ni)
                    acc[mi][ni] = __builtin_amdgcn_mfma_f32_16x16x32_bf16(
                        af[mi], b0[ni], acc[mi][ni], 0, 0, 0);
            __builtin_amdgcn_s_setprio(0);
#pragma unroll
            for (int mi = 0; mi < 4; ++mi) {
                int r = (mi + 4) * 16 + lo;
                af[mi] = *(const bf16x8*)&ab[r * BK + ((hi4 ^ (r & 7)) << 3)];
            }
            __builtin_amdgcn_s_setprio(1);
#pragma unroll
            for (int mi = 0; mi < 4; ++mi)
#pragma unroll
                for (int ni = 0; ni < 4; ++ni)
                    acc[mi + 4][ni] = __builtin_amdgcn_mfma_f32_16x16x32_bf16(
                        af[mi], b0[ni], acc[mi + 4][ni], 0, 0, 0);
            __builtin_amdgcn_s_setprio(0);
        }

        // ---- A(kk+1) halves 0,1: cvt + swizzled ds_write into dbuf ----
        if (pf) {
            short8 p0, p1;
            CVT2(p0, x0, x1) CVT2(p1, x2, x3)
            *(short8*)&adst[aw0] = p0;
            *(short8*)&adst[aw1] = p1;
        }

        // ---- ks = 1 ----
        {
            bf16x8 af[4];
#pragma unroll
            for (int mi = 0; mi < 4; ++mi) {
                int r = mi * 16 + lo;
                af[mi] = *(const bf16x8*)&ab[r * BK + (((4 | hi4) ^ (r & 7)) << 3)];
            }
            __builtin_amdgcn_s_setprio(1);
#pragma unroll
            for (int mi = 0; mi < 4; ++mi)
#pragma unroll
                for (int ni = 0; ni < 4; ++ni)
                    acc[mi][ni] = __builtin_amdgcn_mfma_f32_16x16x32_bf16(
                        af[mi], b1[ni], acc[mi][ni], 0, 0, 0);
            __builtin_amdgcn_s_setprio(0);
#pragma unroll
            for (int mi = 0; mi < 4; ++mi) {
                int r = (mi + 4) * 16 + lo;
                af[mi] = *(const bf16x8*)&ab[r * BK + (((4 | hi4) ^ (r & 7)) << 3)];
            }
            __builtin_amdgcn_s_setprio(1);
#pragma unroll
            for (int mi = 0; mi < 4; ++mi)
#pragma unroll
                for (int ni = 0; ni < 4; ++ni)
                    acc[mi + 4][ni] = __builtin_amdgcn_mfma_f32_16x16x32_bf16(
                        af[mi], b1[ni], acc[mi + 4][ni], 0, 0, 0);
            __builtin_amdgcn_s_setprio(0);
        }

        // ---- A(kk+1) halves 2,3 ----
        if (pf) {
            short8 p2, p3;
            CVT2(p2, x4, x5) CVT2(p3, x6, x7)
            *(short8*)&adst[aw2] = p2;
            *(short8*)&adst[aw3] = p3;
        }

        // ---- single barrier per kstep ----
        asm volatile("s_waitcnt lgkmcnt(0)" ::: "memory");
        __builtin_amdgcn_s_barrier();
    }
#undef CVT2

    // ---- epilogue: bias-add (hid part), softmax over b, v-dot partial over 256 h ----
    {
        float hp[2][4][4];
#pragma unroll
        for (int par = 0; par < 2; ++par)
#pragma unroll
            for (int j = 0; j < 4; ++j) {
                int b = par * 16 + hi4 * 4 + j;
#pragma unroll
                for (int ni = 0; ni < 4; ++ni)
                    hp[par][j][ni] = hidproj[b * H_ + cblk * 64 + ni * 16 + lo];
            }
#pragma unroll
        for (int mi = 0; mi < 8; ++mi)
#pragma unroll
            for (int ni = 0; ni < 4; ++ni)
#pragma unroll
                for (int j = 0; j < 4; ++j)
                    acc[mi][ni][j] += hp[mi & 1][j][ni];
    }

    float vh[4];
#pragma unroll
    for (int ni = 0; ni < 4; ++ni) vh[ni] = vvec[cblk * 64 + ni * 16 + lo];

    float scp[8][4];
#pragma unroll
    for (int tl = 0; tl < 4; ++tl) {
        const int m0 = tl * 2, m1 = tl * 2 + 1;
#pragma unroll
        for (int ni = 0; ni < 4; ++ni) {
            float mx = -1e30f;
#pragma unroll
            for (int j = 0; j < 4; ++j) {
                mx = fmaxf(mx, acc[m0][ni][j]);
                mx = fmaxf(mx, acc[m1][ni][j]);
            }
            mx = fmaxf(mx, __shfl_xor(mx, 16));
            mx = fmaxf(mx, __shfl_xor(mx, 32));
            float e0[4], e1[4];
            float sum = 0.f;
#pragma unroll
            for (int j = 0; j < 4; ++j) {
                e0[j] = __expf(acc[m0][ni][j] - mx);
                e1[j] = __expf(acc[m1][ni][j] - mx);
                sum += e0[j] + e1[j];
            }
            sum += __shfl_xor(sum, 16);
            sum += __shfl_xor(sum, 32);
            float rs = vh[ni] / sum;
#pragma unroll
            for (int j = 0; j < 4; ++j) {
                if (ni == 0) { scp[m0][j] = e0[j] * rs; scp[m1][j] = e1[j] * rs; }
                else         { scp[m0][j] += e0[j] * rs; scp[m1][j] += e1[j] * rs; }
            }
        }
    }

#pragma unroll
    for (int mi = 0; mi < 8; ++mi)
#pragma unroll
        for (int j = 0; j < 4; ++j) {
            float x = scp[mi][j];
            x += __shfl_xor(x, 1);
            x += __shfl_xor(x, 2);
            x += __shfl_xor(x, 4);
            x += __shfl_xor(x, 8);
            scp[mi][j] = x;
        }

    __syncthreads();
    float* red = (float*)&lds_a[0][0];   // [4][128]
    if (lo == 0) {
#pragma unroll
        for (int mi = 0; mi < 8; ++mi)
#pragma unroll
            for (int j = 0; j < 4; ++j)
                red[wid * 128 + mi * 16 + hi4 * 4 + j] = scp[mi][j];
    }
    __syncthreads();
    if (tid < 128) {
        float s = red[tid] + red[128 + tid] + red[256 + tid] + red[384 + tid];
        int b  = tid & 31;
        int tl = tid >> 5;
        spart[(size_t)eta * 131072 + (size_t)b * T_ + (t0 + tl)] = s;
    }
}

extern "C" void kernel_launch(void* const* d_in, const int* in_sizes, int n_in,
                              void* d_out, int out_size, void* d_ws, size_t ws_size,
                              hipStream_t stream) {
    const float* hidden = (const float*)d_in[0];
    const float* enc    = (const float*)d_in[1];
    const float* W      = (const float*)d_in[2];
    const float* bias   = (const float*)d_in[3];
    const float* v      = (const float*)d_in[4];
    float* out = (float*)d_out;

    float* hidproj = (float*)d_ws;                       // 64 KB
    short* w2f     = (short*)((char*)d_ws + 65536);      // 512 KB
    float* spart   = (float*)((char*)d_ws + 65536 + 524288); // 1 MB (2 x 131072 f32)

    prep_w2f<<<1024, 256, 0, stream>>>(W, w2f);
    prep_hid<<<dim3(4, 32), 128, 0, stream>>>(hidden, W, bias, hidproj);
    attn_main<<<2048, NTHREADS, 0, stream>>>(enc, hidproj, w2f, v, spart);
    finish<<<512, 256, 0, stream>>>(spart, out);
}